// Round 9
// baseline (984.571 us; speedup 1.0000x reference)
//
#include <hip/hip_runtime.h>

#define D 128
#define CAP 48            // per-node slot capacity; max degree ~36 for Poisson(16)
#define PSHIFT 8
#define PNODES 256        // nodes per partition (1 << PSHIFT)
#define CAPP 6144         // per-partition edge capacity (mean 4092, sigma ~64)
#define GB 512            // gemm block threads (8 waves)
#define CHUNK_P 64        // rows per gemm chunk

typedef unsigned short u16;

// ---------------- bf16 helpers ----------------

__device__ __forceinline__ u16 f2bf(float f) {           // RNE
    unsigned u = __float_as_uint(f);
    return (u16)((u + 0x7FFFu + ((u >> 16) & 1u)) >> 16);
}

__device__ __forceinline__ float bf2f(u16 h) {
    return __uint_as_float((unsigned)h << 16);
}

__device__ __forceinline__ float4 bf2f4(ushort4 h) {
    float4 f;
    f.x = bf2f(h.x); f.y = bf2f(h.y); f.z = bf2f(h.z); f.w = bf2f(h.w);
    return f;
}

__device__ __forceinline__ ushort4 f2bf4(float4 a) {
    ushort4 r;
    r.x = f2bf(a.x); r.y = f2bf(a.y); r.z = f2bf(a.z); r.w = f2bf(a.w);
    return r;
}

__device__ __forceinline__ void fma4(float4& acc, float xs, const float4& wv) {
    acc.x = fmaf(xs, wv.x, acc.x);
    acc.y = fmaf(xs, wv.y, acc.y);
    acc.z = fmaf(xs, wv.z, acc.z);
    acc.w = fmaf(xs, wv.w, acc.w);
}

// ---------------- build phase A: radix partition by dst>>8 ----------------
// Atomics hit only P=391 hot counters (L2-resident, pipelined); appended
// (s,d) records are temporally sequential per partition -> writes merge in
// the memory-side LLC. Replaces 1.6M cold atomics + 96 MB granule scatter.

__global__ void k_part(const int* __restrict__ src, const int* __restrict__ dstv,
                       int* __restrict__ pcur, int2* __restrict__ plist, int E) {
    int e0 = blockIdx.x * 256 + threadIdx.x;
    int step = gridDim.x * 256;
    for (int e = e0; e < E; e += step) {
        int s = src[e], d = dstv[e];
        int p = d >> PSHIFT;
        int pos = atomicAdd(&pcur[p], 1);
        if (pos < CAPP) plist[(size_t)p * CAPP + pos] = make_int2(s, d);
    }
}

// ---------------- build phase B: per-partition slot build in LDS ----------------
// One block per partition; counts + slot scatter entirely in LDS, then one
// coalesced 49 KB write-out. Zero global random writes.

__global__ __launch_bounds__(256) void k_build2(const int2* __restrict__ plist,
                                                const int* __restrict__ pcur,
                                                int* __restrict__ cnt,
                                                int* __restrict__ slots, int N) {
    __shared__ int cnt_l[PNODES];          // 1 KB
    __shared__ int slots_l[PNODES * CAP];  // 48 KB
    int p = blockIdx.x;
    int node0 = p << PSHIFT;
    int nnodes = min(PNODES, N - node0);

    for (int t = threadIdx.x; t < PNODES; t += 256) cnt_l[t] = 0;
    __syncthreads();

    int nE = min(pcur[p], CAPP);
    for (int i = threadIdx.x; i < nE; i += 256) {
        int2 ed = plist[(size_t)p * CAPP + i];
        int ln = ed.y - node0;             // in [0, PNODES)
        int q = atomicAdd(&cnt_l[ln], 1);  // LDS atomic
        if (q < CAP) slots_l[ln * CAP + q] = ed.x;
    }
    __syncthreads();

    for (int t = threadIdx.x; t < nnodes; t += 256) cnt[node0 + t] = cnt_l[t];
    int tot = nnodes * CAP;
    int* gs = slots + (size_t)node0 * CAP;
    for (int i = threadIdx.x; i < tot; i += 256) gs[i] = slots_l[i];
}

__global__ void k_dis(const int* __restrict__ cnt, float* __restrict__ dis, int N) {
    int i = blockIdx.x * 256 + threadIdx.x;
    if (i < N) dis[i] = rsqrtf((float)(cnt[i] + 1));  // deg = indeg + self-loop
}

// ---------------- 4-row gemm micro-tile ----------------

__device__ __forceinline__ void gemm_rows4(const float* __restrict__ xp, const float* sW,
                                           int cg, u16* __restrict__ hp) {
    float4 a0 = {0, 0, 0, 0}, a1 = {0, 0, 0, 0}, a2 = {0, 0, 0, 0}, a3 = {0, 0, 0, 0};
#pragma unroll 8
    for (int kk = 0; kk < D; kk += 4) {
        float4 w0 = *(const float4*)&sW[(kk + 0) * D + cg];
        float4 w1 = *(const float4*)&sW[(kk + 1) * D + cg];
        float4 w2 = *(const float4*)&sW[(kk + 2) * D + cg];
        float4 w3 = *(const float4*)&sW[(kk + 3) * D + cg];
        float4 x0 = *(const float4*)&xp[0 * D + kk];
        float4 x1 = *(const float4*)&xp[1 * D + kk];
        float4 x2 = *(const float4*)&xp[2 * D + kk];
        float4 x3 = *(const float4*)&xp[3 * D + kk];
        fma4(a0, x0.x, w0); fma4(a0, x0.y, w1); fma4(a0, x0.z, w2); fma4(a0, x0.w, w3);
        fma4(a1, x1.x, w0); fma4(a1, x1.y, w1); fma4(a1, x1.z, w2); fma4(a1, x1.w, w3);
        fma4(a2, x2.x, w0); fma4(a2, x2.y, w1); fma4(a2, x2.z, w2); fma4(a2, x2.w, w3);
        fma4(a3, x3.x, w0); fma4(a3, x3.y, w1); fma4(a3, x3.z, w2); fma4(a3, x3.w, w3);
    }
    *(ushort4*)&hp[0 * D] = f2bf4(a0);
    *(ushort4*)&hp[1 * D] = f2bf4(a1);
    *(ushort4*)&hp[2 * D] = f2bf4(a2);
    *(ushort4*)&hp[3 * D] = f2bf4(a3);
}

// ---------------- GEMM: H(bf16) = X(fp32) @ W  (W staged in LDS) ----------------

__global__ __launch_bounds__(GB) void k_gemm(const float* __restrict__ X,
                                             const float* __restrict__ Wg,
                                             u16* __restrict__ H, int nchunks, int N) {
    __shared__ float sW[D * D];  // 64 KB
    for (int i = threadIdx.x; i < D * D / 4; i += GB)
        ((float4*)sW)[i] = ((const float4*)Wg)[i];
    __syncthreads();

    int r0 = (threadIdx.x >> 5) << 2;   // 0..60
    int cg = (threadIdx.x & 31) << 2;   // 0..124

    for (int chunk = blockIdx.x; chunk < nchunks; chunk += gridDim.x) {
        int row0 = chunk * CHUNK_P + r0;
        if (row0 >= N) continue;
        size_t base = (size_t)row0 * D;
        gemm_rows4(X + base, sW, cg, H + base + cg);
    }
}

// ---------------- Aggregation: Y(fp32) = A_norm @ H(bf16) + b ----------------
// Half-wave (32 lanes x 4 bf16 = 256 B) per dst node; edge loop unrolled x8.

__global__ __launch_bounds__(256) void k_agg(const u16* __restrict__ H,
                                             const int* __restrict__ slots,
                                             const int* __restrict__ cnt,
                                             const float* __restrict__ dis,
                                             const float* __restrict__ bias,
                                             float* __restrict__ Y, int N, int relu) {
    int node = (blockIdx.x * 256 + threadIdx.x) >> 5;  // half-wave per node
    int lane = threadIdx.x & 31;
    if (node >= N) return;

    const ushort4* __restrict__ Hv = (const ushort4*)H;  // 32 ushort4 per row

    float ds = dis[node];
    float4 hv = bf2f4(Hv[(size_t)node * 32 + lane]);
    float wl = ds * ds;  // self-loop norm
    float4 acc;
    acc.x = wl * hv.x; acc.y = wl * hv.y; acc.z = wl * hv.z; acc.w = wl * hv.w;

    int n = cnt[node];
    if (n > CAP) n = CAP;
    const int* sp = slots + (size_t)node * CAP;

    int e = 0;
    for (; e + 8 <= n; e += 8) {
        int s0 = sp[e + 0], s1 = sp[e + 1], s2 = sp[e + 2], s3 = sp[e + 3];
        int s4 = sp[e + 4], s5 = sp[e + 5], s6 = sp[e + 6], s7 = sp[e + 7];
        ushort4 v0 = Hv[(size_t)s0 * 32 + lane];
        ushort4 v1 = Hv[(size_t)s1 * 32 + lane];
        ushort4 v2 = Hv[(size_t)s2 * 32 + lane];
        ushort4 v3 = Hv[(size_t)s3 * 32 + lane];
        ushort4 v4 = Hv[(size_t)s4 * 32 + lane];
        ushort4 v5 = Hv[(size_t)s5 * 32 + lane];
        ushort4 v6 = Hv[(size_t)s6 * 32 + lane];
        ushort4 v7 = Hv[(size_t)s7 * 32 + lane];
        float w0 = dis[s0] * ds, w1 = dis[s1] * ds, w2 = dis[s2] * ds, w3 = dis[s3] * ds;
        float w4 = dis[s4] * ds, w5 = dis[s5] * ds, w6 = dis[s6] * ds, w7 = dis[s7] * ds;
        fma4(acc, w0, bf2f4(v0));
        fma4(acc, w1, bf2f4(v1));
        fma4(acc, w2, bf2f4(v2));
        fma4(acc, w3, bf2f4(v3));
        fma4(acc, w4, bf2f4(v4));
        fma4(acc, w5, bf2f4(v5));
        fma4(acc, w6, bf2f4(v6));
        fma4(acc, w7, bf2f4(v7));
    }
    for (; e < n; ++e) {
        int s = sp[e];
        ushort4 v = Hv[(size_t)s * 32 + lane];
        fma4(acc, dis[s] * ds, bf2f4(v));
    }

    float4 bv = ((const float4*)bias)[lane];
    acc.x += bv.x; acc.y += bv.y; acc.z += bv.z; acc.w += bv.w;
    if (relu) {
        acc.x = fmaxf(acc.x, 0.f);
        acc.y = fmaxf(acc.y, 0.f);
        acc.z = fmaxf(acc.z, 0.f);
        acc.w = fmaxf(acc.w, 0.f);
    }
    ((float4*)(Y + (size_t)node * D))[lane] = acc;
}

// ---------------- launch ----------------

extern "C" void kernel_launch(void* const* d_in, const int* in_sizes, int n_in,
                              void* d_out, int out_size, void* d_ws, size_t ws_size,
                              hipStream_t stream) {
    const float* x  = (const float*)d_in[0];
    const int*   ei = (const int*)d_in[1];
    const float* W1 = (const float*)d_in[2];
    const float* b1 = (const float*)d_in[3];
    const float* W2 = (const float*)d_in[4];
    const float* b2 = (const float*)d_in[5];
    const float* W3 = (const float*)d_in[6];
    const float* b3 = (const float*)d_in[7];
    float* out = (float*)d_out;

    int N = in_sizes[0] / D;
    int E = in_sizes[1] / 2;
    const int* src  = ei;       // edge_index[0]
    const int* dstv = ei + E;   // edge_index[1]
    int P = (N + PNODES - 1) >> PSHIFT;  // 391

    char* ws = (char*)d_ws;
    size_t off = 0;
    auto alloc = [&](size_t bytes) -> void* {
        void* p = ws + off;
        off += (bytes + 255) & ~(size_t)255;
        return p;
    };
    u16*   Hbuf  = (u16*)alloc((size_t)N * D * sizeof(u16));        // 25.6 MB
    int*   cnt   = (int*)alloc((size_t)N * sizeof(int));            // 0.4 MB
    int*   slots = (int*)alloc((size_t)N * CAP * sizeof(int));      // 19.2 MB
    float* dis   = (float*)alloc((size_t)N * sizeof(float));        // 0.4 MB
    int*   pcur  = (int*)alloc((size_t)P * sizeof(int));            // 1.6 KB
    int2*  plist = (int2*)alloc((size_t)P * CAPP * sizeof(int2));   // 19.2 MB

    int nchunks = (N + CHUNK_P - 1) / CHUNK_P;  // 1563
    int gemmgrid = 512;                         // 2 blocks/CU resident
    int aggblocks = (N + 7) / 8;

    // --- build: partition (phase A) -> LDS slot build (phase B) -> dis ---
    hipMemsetAsync(pcur, 0, (size_t)P * sizeof(int), stream);
    k_part<<<2048, 256, 0, stream>>>(src, dstv, pcur, plist, E);
    k_build2<<<P, 256, 0, stream>>>(plist, pcur, cnt, slots, N);
    k_dis<<<(N + 255) / 256, 256, 0, stream>>>(cnt, dis, N);

    // --- layer 1 ---
    k_gemm<<<gemmgrid, GB, 0, stream>>>(x, W1, Hbuf, nchunks, N);
    k_agg<<<aggblocks, 256, 0, stream>>>(Hbuf, slots, cnt, dis, b1, out, N, 1);

    // --- layer 2 ---
    k_gemm<<<gemmgrid, GB, 0, stream>>>(out, W2, Hbuf, nchunks, N);
    k_agg<<<aggblocks, 256, 0, stream>>>(Hbuf, slots, cnt, dis, b2, out, N, 1);

    // --- layer 3 (no relu) ---
    k_gemm<<<gemmgrid, GB, 0, stream>>>(out, W3, Hbuf, nchunks, N);
    k_agg<<<aggblocks, 256, 0, stream>>>(Hbuf, slots, cnt, dis, b3, out, N, 0);
}

// Round 10
// 438.298 us; speedup vs baseline: 2.2463x; 2.2463x over previous
//
#include <hip/hip_runtime.h>

#define D 128
#define CAP 48            // per-node slot capacity; max degree ~36 for Poisson(16)
#define PSHIFT 8
#define PNODES 256        // nodes per partition
#define PMAX 512          // compile-time max partitions (N <= 131072)
#define CAPP 6144         // per-partition edge capacity (mean 4092, sigma ~64)
#define EPB 8192          // edges per k_part block
#define GB 512            // gemm block threads (8 waves)
#define CHUNK_P 64        // rows per gemm chunk

typedef unsigned short u16;

// ---------------- bf16 helpers ----------------

__device__ __forceinline__ u16 f2bf(float f) {           // RNE
    unsigned u = __float_as_uint(f);
    return (u16)((u + 0x7FFFu + ((u >> 16) & 1u)) >> 16);
}

__device__ __forceinline__ float bf2f(u16 h) {
    return __uint_as_float((unsigned)h << 16);
}

__device__ __forceinline__ float4 bf2f4(ushort4 h) {
    float4 f;
    f.x = bf2f(h.x); f.y = bf2f(h.y); f.z = bf2f(h.z); f.w = bf2f(h.w);
    return f;
}

__device__ __forceinline__ ushort4 f2bf4(float4 a) {
    ushort4 r;
    r.x = f2bf(a.x); r.y = f2bf(a.y); r.z = f2bf(a.z); r.w = f2bf(a.w);
    return r;
}

__device__ __forceinline__ void fma4(float4& acc, float xs, const float4& wv) {
    acc.x = fmaf(xs, wv.x, acc.x);
    acc.y = fmaf(xs, wv.y, acc.y);
    acc.z = fmaf(xs, wv.z, acc.z);
    acc.w = fmaf(xs, wv.w, acc.w);
}

// ---------------- build phase A: LDS-privatized radix partition ----------------
// Round-9 lesson: 391 hot GLOBAL counters serialize (558 us). Privatize the
// histogram in LDS, reserve per-block bases with ONE global atomic per
// partition per block (<=196 per address), then append edges at base_l[p]++.
// Record packs (src<<8 | d&255) into 4 B; per-partition runs ~21 records merge
// into full granules.

__global__ __launch_bounds__(1024) void k_part(const int* __restrict__ src,
                                               const int* __restrict__ dstv,
                                               int* __restrict__ pcur,
                                               int* __restrict__ plist, int E, int P) {
    __shared__ int hist_l[PMAX];
    __shared__ int base_l[PMAX];
    int e0 = blockIdx.x * EPB;
    int e1 = min(e0 + EPB, E);

    for (int i = threadIdx.x; i < P; i += 1024) hist_l[i] = 0;
    __syncthreads();

    for (int e = e0 + threadIdx.x; e < e1; e += 1024)
        atomicAdd(&hist_l[dstv[e] >> PSHIFT], 1);
    __syncthreads();

    for (int i = threadIdx.x; i < P; i += 1024)
        base_l[i] = atomicAdd(&pcur[i], hist_l[i]);
    __syncthreads();

    for (int e = e0 + threadIdx.x; e < e1; e += 1024) {
        int s = src[e], d = dstv[e];
        int p = d >> PSHIFT;
        int pos = atomicAdd(&base_l[p], 1);   // LDS atomic
        if (pos < CAPP)
            plist[(size_t)p * CAPP + pos] = (s << PSHIFT) | (d & (PNODES - 1));
    }
}

// ---------------- build phase B: per-partition slot build in LDS ----------------

__global__ __launch_bounds__(256) void k_build2(const int* __restrict__ plist,
                                                const int* __restrict__ pcur,
                                                int* __restrict__ cnt,
                                                int* __restrict__ slots, int N) {
    __shared__ int cnt_l[PNODES];          // 1 KB
    __shared__ int slots_l[PNODES * CAP];  // 48 KB
    int p = blockIdx.x;
    int node0 = p << PSHIFT;
    int nnodes = min(PNODES, N - node0);

    for (int t = threadIdx.x; t < PNODES; t += 256) cnt_l[t] = 0;
    __syncthreads();

    int nE = min(pcur[p], CAPP);
    for (int i = threadIdx.x; i < nE; i += 256) {
        int v = plist[(size_t)p * CAPP + i];
        int ln = v & (PNODES - 1);
        int s = (unsigned)v >> PSHIFT;
        int q = atomicAdd(&cnt_l[ln], 1);  // LDS atomic
        if (q < CAP) slots_l[ln * CAP + q] = s;
    }
    __syncthreads();

    for (int t = threadIdx.x; t < nnodes; t += 256) cnt[node0 + t] = cnt_l[t];
    int tot = nnodes * CAP;
    int* gs = slots + (size_t)node0 * CAP;
    for (int i = threadIdx.x; i < tot; i += 256) gs[i] = slots_l[i];
}

__global__ void k_dis(const int* __restrict__ cnt, float* __restrict__ dis, int N) {
    int i = blockIdx.x * 256 + threadIdx.x;
    if (i < N) dis[i] = rsqrtf((float)(cnt[i] + 1));  // deg = indeg + self-loop
}

// ---------------- 4-row gemm micro-tile ----------------

__device__ __forceinline__ void gemm_rows4(const float* __restrict__ xp, const float* sW,
                                           int cg, u16* __restrict__ hp) {
    float4 a0 = {0, 0, 0, 0}, a1 = {0, 0, 0, 0}, a2 = {0, 0, 0, 0}, a3 = {0, 0, 0, 0};
#pragma unroll 8
    for (int kk = 0; kk < D; kk += 4) {
        float4 w0 = *(const float4*)&sW[(kk + 0) * D + cg];
        float4 w1 = *(const float4*)&sW[(kk + 1) * D + cg];
        float4 w2 = *(const float4*)&sW[(kk + 2) * D + cg];
        float4 w3 = *(const float4*)&sW[(kk + 3) * D + cg];
        float4 x0 = *(const float4*)&xp[0 * D + kk];
        float4 x1 = *(const float4*)&xp[1 * D + kk];
        float4 x2 = *(const float4*)&xp[2 * D + kk];
        float4 x3 = *(const float4*)&xp[3 * D + kk];
        fma4(a0, x0.x, w0); fma4(a0, x0.y, w1); fma4(a0, x0.z, w2); fma4(a0, x0.w, w3);
        fma4(a1, x1.x, w0); fma4(a1, x1.y, w1); fma4(a1, x1.z, w2); fma4(a1, x1.w, w3);
        fma4(a2, x2.x, w0); fma4(a2, x2.y, w1); fma4(a2, x2.z, w2); fma4(a2, x2.w, w3);
        fma4(a3, x3.x, w0); fma4(a3, x3.y, w1); fma4(a3, x3.z, w2); fma4(a3, x3.w, w3);
    }
    *(ushort4*)&hp[0 * D] = f2bf4(a0);
    *(ushort4*)&hp[1 * D] = f2bf4(a1);
    *(ushort4*)&hp[2 * D] = f2bf4(a2);
    *(ushort4*)&hp[3 * D] = f2bf4(a3);
}

// ---------------- GEMM: H(bf16) = X(fp32) @ W  (W staged in LDS) ----------------

__global__ __launch_bounds__(GB) void k_gemm(const float* __restrict__ X,
                                             const float* __restrict__ Wg,
                                             u16* __restrict__ H, int nchunks, int N) {
    __shared__ float sW[D * D];  // 64 KB
    for (int i = threadIdx.x; i < D * D / 4; i += GB)
        ((float4*)sW)[i] = ((const float4*)Wg)[i];
    __syncthreads();

    int r0 = (threadIdx.x >> 5) << 2;   // 0..60
    int cg = (threadIdx.x & 31) << 2;   // 0..124

    for (int chunk = blockIdx.x; chunk < nchunks; chunk += gridDim.x) {
        int row0 = chunk * CHUNK_P + r0;
        if (row0 >= N) continue;
        size_t base = (size_t)row0 * D;
        gemm_rows4(X + base, sW, cg, H + base + cg);
    }
}

// ---------------- Aggregation: Y(fp32) = A_norm @ H(bf16) + b ----------------
// Half-wave (32 lanes x 4 bf16 = 256 B) per dst node; edge loop unrolled x8.

__global__ __launch_bounds__(256) void k_agg(const u16* __restrict__ H,
                                             const int* __restrict__ slots,
                                             const int* __restrict__ cnt,
                                             const float* __restrict__ dis,
                                             const float* __restrict__ bias,
                                             float* __restrict__ Y, int N, int relu) {
    int node = (blockIdx.x * 256 + threadIdx.x) >> 5;  // half-wave per node
    int lane = threadIdx.x & 31;
    if (node >= N) return;

    const ushort4* __restrict__ Hv = (const ushort4*)H;  // 32 ushort4 per row

    float ds = dis[node];
    float4 hv = bf2f4(Hv[(size_t)node * 32 + lane]);
    float wl = ds * ds;  // self-loop norm
    float4 acc;
    acc.x = wl * hv.x; acc.y = wl * hv.y; acc.z = wl * hv.z; acc.w = wl * hv.w;

    int n = cnt[node];
    if (n > CAP) n = CAP;
    const int* sp = slots + (size_t)node * CAP;

    int e = 0;
    for (; e + 8 <= n; e += 8) {
        int s0 = sp[e + 0], s1 = sp[e + 1], s2 = sp[e + 2], s3 = sp[e + 3];
        int s4 = sp[e + 4], s5 = sp[e + 5], s6 = sp[e + 6], s7 = sp[e + 7];
        ushort4 v0 = Hv[(size_t)s0 * 32 + lane];
        ushort4 v1 = Hv[(size_t)s1 * 32 + lane];
        ushort4 v2 = Hv[(size_t)s2 * 32 + lane];
        ushort4 v3 = Hv[(size_t)s3 * 32 + lane];
        ushort4 v4 = Hv[(size_t)s4 * 32 + lane];
        ushort4 v5 = Hv[(size_t)s5 * 32 + lane];
        ushort4 v6 = Hv[(size_t)s6 * 32 + lane];
        ushort4 v7 = Hv[(size_t)s7 * 32 + lane];
        float w0 = dis[s0] * ds, w1 = dis[s1] * ds, w2 = dis[s2] * ds, w3 = dis[s3] * ds;
        float w4 = dis[s4] * ds, w5 = dis[s5] * ds, w6 = dis[s6] * ds, w7 = dis[s7] * ds;
        fma4(acc, w0, bf2f4(v0));
        fma4(acc, w1, bf2f4(v1));
        fma4(acc, w2, bf2f4(v2));
        fma4(acc, w3, bf2f4(v3));
        fma4(acc, w4, bf2f4(v4));
        fma4(acc, w5, bf2f4(v5));
        fma4(acc, w6, bf2f4(v6));
        fma4(acc, w7, bf2f4(v7));
    }
    for (; e < n; ++e) {
        int s = sp[e];
        ushort4 v = Hv[(size_t)s * 32 + lane];
        fma4(acc, dis[s] * ds, bf2f4(v));
    }

    float4 bv = ((const float4*)bias)[lane];
    acc.x += bv.x; acc.y += bv.y; acc.z += bv.z; acc.w += bv.w;
    if (relu) {
        acc.x = fmaxf(acc.x, 0.f);
        acc.y = fmaxf(acc.y, 0.f);
        acc.z = fmaxf(acc.z, 0.f);
        acc.w = fmaxf(acc.w, 0.f);
    }
    ((float4*)(Y + (size_t)node * D))[lane] = acc;
}

// ---------------- launch ----------------

extern "C" void kernel_launch(void* const* d_in, const int* in_sizes, int n_in,
                              void* d_out, int out_size, void* d_ws, size_t ws_size,
                              hipStream_t stream) {
    const float* x  = (const float*)d_in[0];
    const int*   ei = (const int*)d_in[1];
    const float* W1 = (const float*)d_in[2];
    const float* b1 = (const float*)d_in[3];
    const float* W2 = (const float*)d_in[4];
    const float* b2 = (const float*)d_in[5];
    const float* W3 = (const float*)d_in[6];
    const float* b3 = (const float*)d_in[7];
    float* out = (float*)d_out;

    int N = in_sizes[0] / D;
    int E = in_sizes[1] / 2;
    const int* src  = ei;       // edge_index[0]
    const int* dstv = ei + E;   // edge_index[1]
    int P = (N + PNODES - 1) >> PSHIFT;  // 391

    char* ws = (char*)d_ws;
    size_t off = 0;
    auto alloc = [&](size_t bytes) -> void* {
        void* p = ws + off;
        off += (bytes + 255) & ~(size_t)255;
        return p;
    };
    u16*   Hbuf  = (u16*)alloc((size_t)N * D * sizeof(u16));        // 25.6 MB
    int*   cnt   = (int*)alloc((size_t)N * sizeof(int));            // 0.4 MB
    int*   slots = (int*)alloc((size_t)N * CAP * sizeof(int));      // 19.2 MB
    float* dis   = (float*)alloc((size_t)N * sizeof(float));        // 0.4 MB
    int*   pcur  = (int*)alloc((size_t)P * sizeof(int));            // 1.6 KB
    int*   plist = (int*)alloc((size_t)P * CAPP * sizeof(int));     // 9.6 MB

    int nchunks = (N + CHUNK_P - 1) / CHUNK_P;  // 1563
    int gemmgrid = 512;                         // 2 blocks/CU resident
    int aggblocks = (N + 7) / 8;
    int pablocks = (E + EPB - 1) / EPB;         // 196

    // --- build: LDS-privatized partition -> LDS slot build -> dis ---
    hipMemsetAsync(pcur, 0, (size_t)P * sizeof(int), stream);
    k_part<<<pablocks, 1024, 0, stream>>>(src, dstv, pcur, plist, E, P);
    k_build2<<<P, 256, 0, stream>>>(plist, pcur, cnt, slots, N);
    k_dis<<<(N + 255) / 256, 256, 0, stream>>>(cnt, dis, N);

    // --- layer 1 ---
    k_gemm<<<gemmgrid, GB, 0, stream>>>(x, W1, Hbuf, nchunks, N);
    k_agg<<<aggblocks, 256, 0, stream>>>(Hbuf, slots, cnt, dis, b1, out, N, 1);

    // --- layer 2 ---
    k_gemm<<<gemmgrid, GB, 0, stream>>>(out, W2, Hbuf, nchunks, N);
    k_agg<<<aggblocks, 256, 0, stream>>>(Hbuf, slots, cnt, dis, b2, out, N, 1);

    // --- layer 3 (no relu) ---
    k_gemm<<<gemmgrid, GB, 0, stream>>>(out, W3, Hbuf, nchunks, N);
    k_agg<<<aggblocks, 256, 0, stream>>>(Hbuf, slots, cnt, dis, b3, out, N, 0);
}

// Round 11
// 323.512 us; speedup vs baseline: 3.0434x; 1.3548x over previous
//
#include <hip/hip_runtime.h>

#define D 128
#define CAP 48            // per-node slot capacity; max degree ~36 for Poisson(16)
#define PSHIFT 8
#define PNODES 256        // nodes per partition
#define PMAX 512          // compile-time max partitions (N <= 131072)
#define CAPP 6144         // per-partition edge capacity (mean 4092, sigma ~64)
#define EPB 8192          // edges per k_part block

typedef unsigned short u16;
typedef __bf16 bf16_t;
typedef bf16_t bf16x8 __attribute__((ext_vector_type(8)));
typedef float f32x4v __attribute__((ext_vector_type(4)));

// ---------------- bf16 helpers ----------------

__device__ __forceinline__ u16 f2bf(float f) {           // RNE
    unsigned u = __float_as_uint(f);
    return (u16)((u + 0x7FFFu + ((u >> 16) & 1u)) >> 16);
}

__device__ __forceinline__ float bf2f(u16 h) {
    return __uint_as_float((unsigned)h << 16);
}

__device__ __forceinline__ float4 bf2f4(ushort4 h) {
    float4 f;
    f.x = bf2f(h.x); f.y = bf2f(h.y); f.z = bf2f(h.z); f.w = bf2f(h.w);
    return f;
}

__device__ __forceinline__ void fma4(float4& acc, float xs, const float4& wv) {
    acc.x = fmaf(xs, wv.x, acc.x);
    acc.y = fmaf(xs, wv.y, acc.y);
    acc.z = fmaf(xs, wv.z, acc.z);
    acc.w = fmaf(xs, wv.w, acc.w);
}

// ---------------- build phase A: LDS-privatized radix partition ----------------

__global__ __launch_bounds__(1024) void k_part(const int* __restrict__ src,
                                               const int* __restrict__ dstv,
                                               int* __restrict__ pcur,
                                               int* __restrict__ plist, int E, int P) {
    __shared__ int hist_l[PMAX];
    __shared__ int base_l[PMAX];
    int e0 = blockIdx.x * EPB;
    int e1 = min(e0 + EPB, E);

    for (int i = threadIdx.x; i < P; i += 1024) hist_l[i] = 0;
    __syncthreads();

    for (int e = e0 + threadIdx.x; e < e1; e += 1024)
        atomicAdd(&hist_l[dstv[e] >> PSHIFT], 1);
    __syncthreads();

    for (int i = threadIdx.x; i < P; i += 1024)
        base_l[i] = atomicAdd(&pcur[i], hist_l[i]);
    __syncthreads();

    for (int e = e0 + threadIdx.x; e < e1; e += 1024) {
        int s = src[e], d = dstv[e];
        int p = d >> PSHIFT;
        int pos = atomicAdd(&base_l[p], 1);   // LDS atomic
        if (pos < CAPP)
            plist[(size_t)p * CAPP + pos] = (s << PSHIFT) | (d & (PNODES - 1));
    }
}

// ---------------- build phase B: per-partition slot build in LDS ----------------

__global__ __launch_bounds__(256) void k_build2(const int* __restrict__ plist,
                                                const int* __restrict__ pcur,
                                                int* __restrict__ cnt,
                                                int* __restrict__ slots, int N) {
    __shared__ int cnt_l[PNODES];          // 1 KB
    __shared__ int slots_l[PNODES * CAP];  // 48 KB
    int p = blockIdx.x;
    int node0 = p << PSHIFT;
    int nnodes = min(PNODES, N - node0);

    for (int t = threadIdx.x; t < PNODES; t += 256) cnt_l[t] = 0;
    __syncthreads();

    int nE = min(pcur[p], CAPP);
    for (int i = threadIdx.x; i < nE; i += 256) {
        int v = plist[(size_t)p * CAPP + i];
        int ln = v & (PNODES - 1);
        int s = (unsigned)v >> PSHIFT;
        int q = atomicAdd(&cnt_l[ln], 1);  // LDS atomic
        if (q < CAP) slots_l[ln * CAP + q] = s;
    }
    __syncthreads();

    for (int t = threadIdx.x; t < nnodes; t += 256) cnt[node0 + t] = cnt_l[t];
    int tot = nnodes * CAP;
    int* gs = slots + (size_t)node0 * CAP;
    for (int i = threadIdx.x; i < tot; i += 256) gs[i] = slots_l[i];
}

__global__ void k_dis(const int* __restrict__ cnt, float* __restrict__ dis, int N) {
    int i = blockIdx.x * 256 + threadIdx.x;
    if (i < N) dis[i] = rsqrtf((float)(cnt[i] + 1));  // deg = indeg + self-loop
}

// ---------------- MFMA GEMM: H(bf16) = X(fp32) @ W via split-bf16 ----------------
// x = hi + lo (both bf16); X@W ~= Xhi@Whi + Xhi@Wlo + Xlo@Whi (lo@lo ~2^-18,
// dropped). W^T staged in LDS [n][k] bf16 hi/lo with XOR swizzle ^((n&7)<<3)
// so the B-fragment ds_read_b128 (stride 256 B across n) spreads over 8 banks.
// Per block: 4 waves x 32 rows; per wave 2 row-tiles x 8 col-tiles of
// mfma_f32_16x16x32_bf16, K=128 in 4 steps, 192 MFMA per 32x128 chunk.
// Frag layouts: A row=l&15, k=(l>>4)*8+i (consistent guess on A and B cancels
// any k-permutation); C/D col=l&15, row=(l>>4)*4+reg [verified m89].

__global__ __launch_bounds__(256) void k_gemm(const float* __restrict__ X,
                                              const float* __restrict__ Wg,
                                              u16* __restrict__ H, int nchunks, int N) {
    __shared__ bf16_t sHi[D * D];  // 32 KB, W^T [n][k], swizzled
    __shared__ bf16_t sLo[D * D];  // 32 KB

    for (int i = threadIdx.x; i < D * D; i += 256) {
        int k = i >> 7, n = i & 127;        // Wg[i] = W[k][n], coalesced in n
        float w = Wg[i];
        bf16_t hi = (bf16_t)w;
        bf16_t lo = (bf16_t)(w - (float)hi);
        int idx = (n * D + k) ^ ((n & 7) << 3);
        sHi[idx] = hi;
        sLo[idx] = lo;
    }
    __syncthreads();

    int wv = threadIdx.x >> 6;   // wave 0..3
    int l  = threadIdx.x & 63;
    int lm = l & 15;             // A-row / B-col / C-col within tile
    int g  = l >> 4;             // k-group (A/B), row-group (C/D)

    for (int chunk = blockIdx.x; chunk < nchunks; chunk += gridDim.x) {
        int rowbase = chunk * 128 + wv * 32;
        if (rowbase >= N) continue;

        f32x4v acc[2][8];
#pragma unroll
        for (int rt = 0; rt < 2; ++rt)
#pragma unroll
            for (int c = 0; c < 8; ++c)
#pragma unroll
                for (int r = 0; r < 4; ++r) acc[rt][c][r] = 0.f;

#pragma unroll
        for (int t = 0; t < 4; ++t) {
            // --- A fragments from global (fp32 -> hi/lo bf16) ---
            bf16x8 ahi[2], alo[2];
#pragma unroll
            for (int rt = 0; rt < 2; ++rt) {
                int row = rowbase + rt * 16 + lm;
                int rc = row < N ? row : N - 1;          // clamp: loads safe, stores guarded
                const float4* xp = (const float4*)(X + (size_t)rc * D + t * 32 + g * 8);
                float4 f0 = xp[0];
                float4 f1 = xp[1];
                float fv[8] = {f0.x, f0.y, f0.z, f0.w, f1.x, f1.y, f1.z, f1.w};
#pragma unroll
                for (int i = 0; i < 8; ++i) {
                    bf16_t hb = (bf16_t)fv[i];
                    ahi[rt][i] = hb;
                    alo[rt][i] = (bf16_t)(fv[i] - (float)hb);
                }
            }
            // --- B fragments from LDS + MFMA (b shared across both row-tiles) ---
#pragma unroll
            for (int c = 0; c < 8; ++c) {
                int idx = ((c * 16 + lm) * D + t * 32 + g * 8) ^ ((lm & 7) << 3);
                bf16x8 bhi = *(const bf16x8*)&sHi[idx];
                bf16x8 blo = *(const bf16x8*)&sLo[idx];
                acc[0][c] = __builtin_amdgcn_mfma_f32_16x16x32_bf16(ahi[0], bhi, acc[0][c], 0, 0, 0);
                acc[0][c] = __builtin_amdgcn_mfma_f32_16x16x32_bf16(ahi[0], blo, acc[0][c], 0, 0, 0);
                acc[0][c] = __builtin_amdgcn_mfma_f32_16x16x32_bf16(alo[0], bhi, acc[0][c], 0, 0, 0);
                acc[1][c] = __builtin_amdgcn_mfma_f32_16x16x32_bf16(ahi[1], bhi, acc[1][c], 0, 0, 0);
                acc[1][c] = __builtin_amdgcn_mfma_f32_16x16x32_bf16(ahi[1], blo, acc[1][c], 0, 0, 0);
                acc[1][c] = __builtin_amdgcn_mfma_f32_16x16x32_bf16(alo[1], bhi, acc[1][c], 0, 0, 0);
            }
        }

        // --- epilogue: C/D col=lm, row=g*4+r ---
#pragma unroll
        for (int rt = 0; rt < 2; ++rt)
#pragma unroll
            for (int r = 0; r < 4; ++r) {
                int row = rowbase + rt * 16 + g * 4 + r;
                if (row >= N) continue;
                u16* hp = H + (size_t)row * D + lm;
#pragma unroll
                for (int c = 0; c < 8; ++c)
                    hp[c * 16] = f2bf(acc[rt][c][r]);
            }
    }
}

// ---------------- Aggregation: Y(fp32) = A_norm @ H(bf16) + b ----------------

__global__ __launch_bounds__(256) void k_agg(const u16* __restrict__ H,
                                             const int* __restrict__ slots,
                                             const int* __restrict__ cnt,
                                             const float* __restrict__ dis,
                                             const float* __restrict__ bias,
                                             float* __restrict__ Y, int N, int relu) {
    int node = (blockIdx.x * 256 + threadIdx.x) >> 5;  // half-wave per node
    int lane = threadIdx.x & 31;
    if (node >= N) return;

    const ushort4* __restrict__ Hv = (const ushort4*)H;  // 32 ushort4 per row

    float ds = dis[node];
    float4 hv = bf2f4(Hv[(size_t)node * 32 + lane]);
    float wl = ds * ds;  // self-loop norm
    float4 acc;
    acc.x = wl * hv.x; acc.y = wl * hv.y; acc.z = wl * hv.z; acc.w = wl * hv.w;

    int n = cnt[node];
    if (n > CAP) n = CAP;
    const int* sp = slots + (size_t)node * CAP;

    int e = 0;
    for (; e + 8 <= n; e += 8) {
        int s0 = sp[e + 0], s1 = sp[e + 1], s2 = sp[e + 2], s3 = sp[e + 3];
        int s4 = sp[e + 4], s5 = sp[e + 5], s6 = sp[e + 6], s7 = sp[e + 7];
        ushort4 v0 = Hv[(size_t)s0 * 32 + lane];
        ushort4 v1 = Hv[(size_t)s1 * 32 + lane];
        ushort4 v2 = Hv[(size_t)s2 * 32 + lane];
        ushort4 v3 = Hv[(size_t)s3 * 32 + lane];
        ushort4 v4 = Hv[(size_t)s4 * 32 + lane];
        ushort4 v5 = Hv[(size_t)s5 * 32 + lane];
        ushort4 v6 = Hv[(size_t)s6 * 32 + lane];
        ushort4 v7 = Hv[(size_t)s7 * 32 + lane];
        float w0 = dis[s0] * ds, w1 = dis[s1] * ds, w2 = dis[s2] * ds, w3 = dis[s3] * ds;
        float w4 = dis[s4] * ds, w5 = dis[s5] * ds, w6 = dis[s6] * ds, w7 = dis[s7] * ds;
        fma4(acc, w0, bf2f4(v0));
        fma4(acc, w1, bf2f4(v1));
        fma4(acc, w2, bf2f4(v2));
        fma4(acc, w3, bf2f4(v3));
        fma4(acc, w4, bf2f4(v4));
        fma4(acc, w5, bf2f4(v5));
        fma4(acc, w6, bf2f4(v6));
        fma4(acc, w7, bf2f4(v7));
    }
    for (; e < n; ++e) {
        int s = sp[e];
        ushort4 v = Hv[(size_t)s * 32 + lane];
        fma4(acc, dis[s] * ds, bf2f4(v));
    }

    float4 bv = ((const float4*)bias)[lane];
    acc.x += bv.x; acc.y += bv.y; acc.z += bv.z; acc.w += bv.w;
    if (relu) {
        acc.x = fmaxf(acc.x, 0.f);
        acc.y = fmaxf(acc.y, 0.f);
        acc.z = fmaxf(acc.z, 0.f);
        acc.w = fmaxf(acc.w, 0.f);
    }
    ((float4*)(Y + (size_t)node * D))[lane] = acc;
}

// ---------------- launch ----------------

extern "C" void kernel_launch(void* const* d_in, const int* in_sizes, int n_in,
                              void* d_out, int out_size, void* d_ws, size_t ws_size,
                              hipStream_t stream) {
    const float* x  = (const float*)d_in[0];
    const int*   ei = (const int*)d_in[1];
    const float* W1 = (const float*)d_in[2];
    const float* b1 = (const float*)d_in[3];
    const float* W2 = (const float*)d_in[4];
    const float* b2 = (const float*)d_in[5];
    const float* W3 = (const float*)d_in[6];
    const float* b3 = (const float*)d_in[7];
    float* out = (float*)d_out;

    int N = in_sizes[0] / D;
    int E = in_sizes[1] / 2;
    const int* src  = ei;       // edge_index[0]
    const int* dstv = ei + E;   // edge_index[1]
    int P = (N + PNODES - 1) >> PSHIFT;  // 391

    char* ws = (char*)d_ws;
    size_t off = 0;
    auto alloc = [&](size_t bytes) -> void* {
        void* p = ws + off;
        off += (bytes + 255) & ~(size_t)255;
        return p;
    };
    u16*   Hbuf  = (u16*)alloc((size_t)N * D * sizeof(u16));        // 25.6 MB
    int*   cnt   = (int*)alloc((size_t)N * sizeof(int));            // 0.4 MB
    int*   slots = (int*)alloc((size_t)N * CAP * sizeof(int));      // 19.2 MB
    float* dis   = (float*)alloc((size_t)N * sizeof(float));        // 0.4 MB
    int*   pcur  = (int*)alloc((size_t)P * sizeof(int));            // 1.6 KB
    int*   plist = (int*)alloc((size_t)P * CAPP * sizeof(int));     // 9.6 MB

    int nchunks = (N + 127) / 128;   // 782 chunks of 128 rows (4 waves x 32)
    int gemmgrid = 512;              // 2 blocks/CU resident
    int aggblocks = (N + 7) / 8;
    int pablocks = (E + EPB - 1) / EPB;  // 196

    // --- build: LDS-privatized partition -> LDS slot build -> dis ---
    hipMemsetAsync(pcur, 0, (size_t)P * sizeof(int), stream);
    k_part<<<pablocks, 1024, 0, stream>>>(src, dstv, pcur, plist, E, P);
    k_build2<<<P, 256, 0, stream>>>(plist, pcur, cnt, slots, N);
    k_dis<<<(N + 255) / 256, 256, 0, stream>>>(cnt, dis, N);

    // --- layer 1 ---
    k_gemm<<<gemmgrid, 256, 0, stream>>>(x, W1, Hbuf, nchunks, N);
    k_agg<<<aggblocks, 256, 0, stream>>>(Hbuf, slots, cnt, dis, b1, out, N, 1);

    // --- layer 2 ---
    k_gemm<<<gemmgrid, 256, 0, stream>>>(out, W2, Hbuf, nchunks, N);
    k_agg<<<aggblocks, 256, 0, stream>>>(Hbuf, slots, cnt, dis, b2, out, N, 1);

    // --- layer 3 (no relu) ---
    k_gemm<<<gemmgrid, 256, 0, stream>>>(out, W3, Hbuf, nchunks, N);
    k_agg<<<aggblocks, 256, 0, stream>>>(Hbuf, slots, cnt, dis, b3, out, N, 0);
}